// Round 1
// baseline (6201.269 us; speedup 1.0000x reference)
//
#include <hip/hip_runtime.h>
#include <math.h>

#define N_NODES 100000
#define N_EDGES 1600000
#define D_IN 128
#define HIDDEN 128
#define D_OUT 40
#define EPSN 1e-12f

// ---- degree: one atomicAdd per edge ----
__global__ void deg_kernel(const int* __restrict__ dst, float* __restrict__ deg) {
    int e = blockIdx.x * blockDim.x + threadIdx.x;
    if (e < N_EDGES) atomicAdd(&deg[dst[e]], 1.0f);
}

// ---- feature scatter: 32 threads per edge, float4 per thread ----
__global__ void scatter_kernel(const int* __restrict__ src, const int* __restrict__ dst,
                               const float* __restrict__ feat, float* __restrict__ agg) {
    long tid = (long)blockIdx.x * blockDim.x + threadIdx.x;
    long e = tid >> 5;
    int q = (int)(tid & 31);
    if (e >= N_EDGES) return;
    int s = src[e], d = dst[e];
    float4 v = ((const float4*)(feat + (long)s * 128))[q];
    float* o = agg + (long)d * 128 + q * 4;
    atomicAdd(o + 0, v.x);
    atomicAdd(o + 1, v.y);
    atomicAdd(o + 2, v.z);
    atomicAdd(o + 3, v.w);
}

// ---- layer 1: h = relu(normalize(mean@Wl + bl + x@Wr)), 128 threads/node ----
__global__ void layer1_kernel(const float* __restrict__ x, const float* __restrict__ agg,
                              const float* __restrict__ deg,
                              const float* __restrict__ Wl, const float* __restrict__ bl,
                              const float* __restrict__ Wr, float* __restrict__ h) {
    int node = blockIdx.x;
    int j = threadIdx.x;  // 0..127
    __shared__ float sm[128], sx[128], sred[128];
    float dinv = 1.0f / fmaxf(deg[node], 1.0f);
    sm[j] = agg[(long)node * 128 + j] * dinv;
    sx[j] = x[(long)node * 128 + j];
    __syncthreads();
    float acc = bl[j];
#pragma unroll 8
    for (int k = 0; k < 128; k++) {
        acc += sm[k] * Wl[k * 128 + j] + sx[k] * Wr[k * 128 + j];
    }
    sred[j] = acc * acc;
    __syncthreads();
    for (int s = 64; s > 0; s >>= 1) {
        if (j < s) sred[j] += sred[j + s];
        __syncthreads();
    }
    float norm = fmaxf(sqrtf(sred[0]), EPSN);
    float v = acc / norm;
    h[(long)node * 128 + j] = fmaxf(v, 0.0f);
}

// ---- layer 2 + log_softmax: one wave (64 threads) per node, lanes 0..39 active ----
__global__ void layer2_kernel(const float* __restrict__ h, const float* __restrict__ agg,
                              const float* __restrict__ deg,
                              const float* __restrict__ Wl, const float* __restrict__ bl,
                              const float* __restrict__ Wr, float* __restrict__ out) {
    int node = blockIdx.x;
    int t = threadIdx.x;  // 0..63
    __shared__ float sm[128], sh[128];
    float dinv = 1.0f / fmaxf(deg[node], 1.0f);
    sm[t]      = agg[(long)node * 128 + t] * dinv;
    sm[t + 64] = agg[(long)node * 128 + t + 64] * dinv;
    sh[t]      = h[(long)node * 128 + t];
    sh[t + 64] = h[(long)node * 128 + t + 64];
    __syncthreads();
    float o = 0.0f;
    if (t < D_OUT) {
        o = bl[t];
#pragma unroll 8
        for (int k = 0; k < 128; k++) {
            o += sm[k] * Wl[k * D_OUT + t] + sh[k] * Wr[k * D_OUT + t];
        }
    }
    // L2 norm across the 40 active lanes (inactive contribute 0)
    float sq = (t < D_OUT) ? o * o : 0.0f;
    for (int off = 32; off; off >>= 1) sq += __shfl_xor(sq, off, 64);
    float norm = fmaxf(sqrtf(sq), EPSN);
    float v = (t < D_OUT) ? o / norm : -INFINITY;
    // log_softmax over 40
    float m = v;
    for (int off = 32; off; off >>= 1) m = fmaxf(m, __shfl_xor(m, off, 64));
    float ex = (t < D_OUT) ? expf(v - m) : 0.0f;
    float se = ex;
    for (int off = 32; off; off >>= 1) se += __shfl_xor(se, off, 64);
    float ls = logf(se);
    if (t < D_OUT) out[(long)node * D_OUT + t] = v - m - ls;
}

extern "C" void kernel_launch(void* const* d_in, const int* in_sizes, int n_in,
                              void* d_out, int out_size, void* d_ws, size_t ws_size,
                              hipStream_t stream) {
    const float* x   = (const float*)d_in[0];
    const int*   ei  = (const int*)d_in[1];       // [2, E] int32
    const float* Wl1 = (const float*)d_in[2];
    const float* bl1 = (const float*)d_in[3];
    const float* Wr1 = (const float*)d_in[4];
    const float* Wl2 = (const float*)d_in[5];
    const float* bl2 = (const float*)d_in[6];
    const float* Wr2 = (const float*)d_in[7];
    float* out = (float*)d_out;

    const int* src = ei;
    const int* dst = ei + N_EDGES;

    char* ws = (char*)d_ws;
    size_t degBytes = ((size_t)N_NODES * 4 + 255) & ~(size_t)255;
    float* deg = (float*)ws;
    float* agg = (float*)(ws + degBytes);
    float* h   = agg + (size_t)N_NODES * 128;

    hipMemsetAsync(deg, 0, (size_t)N_NODES * 4, stream);
    hipMemsetAsync(agg, 0, (size_t)N_NODES * 128 * 4, stream);

    deg_kernel<<<(N_EDGES + 255) / 256, 256, 0, stream>>>(dst, deg);

    long scatterThreads = (long)N_EDGES * 32;
    int scatterBlocks = (int)((scatterThreads + 255) / 256);
    scatter_kernel<<<scatterBlocks, 256, 0, stream>>>(src, dst, x, agg);

    layer1_kernel<<<N_NODES, 128, 0, stream>>>(x, agg, deg, Wl1, bl1, Wr1, h);

    hipMemsetAsync(agg, 0, (size_t)N_NODES * 128 * 4, stream);
    scatter_kernel<<<scatterBlocks, 256, 0, stream>>>(src, dst, h, agg);

    layer2_kernel<<<N_NODES, 64, 0, stream>>>(h, agg, deg, Wl2, bl2, Wr2, out);
}

// Round 2
// 1081.079 us; speedup vs baseline: 5.7362x; 5.7362x over previous
//
#include <hip/hip_runtime.h>
#include <math.h>

#define N_NODES 100000
#define N_EDGES 1600000
#define D_IN 128
#define HIDDEN 128
#define D_OUT 40
#define EPSN 1e-12f

#define SCAN_CHUNK 1024
#define N_CHUNKS ((N_NODES + SCAN_CHUNK - 1) / SCAN_CHUNK)  // 98

// ---- histogram of destination degrees (int atomics on 100k counters) ----
__global__ void hist_kernel(const int* __restrict__ dst, int* __restrict__ hist) {
    int e = blockIdx.x * blockDim.x + threadIdx.x;
    if (e < N_EDGES) atomicAdd(&hist[dst[e]], 1);
}

// ---- scan pass 1: per-1024-chunk inclusive scan; emit chunk totals ----
__global__ void scan1_kernel(const int* __restrict__ hist, int* __restrict__ incl,
                             int* __restrict__ bsum) {
    __shared__ int sdata[256];
    int t = threadIdx.x;                 // 0..255
    int base = blockIdx.x * SCAN_CHUNK + t * 4;
    int v0 = 0, v1 = 0, v2 = 0, v3 = 0;
    if (base + 0 < N_NODES) v0 = hist[base + 0];
    if (base + 1 < N_NODES) v1 = hist[base + 1];
    if (base + 2 < N_NODES) v2 = hist[base + 2];
    if (base + 3 < N_NODES) v3 = hist[base + 3];
    int tsum = v0 + v1 + v2 + v3;
    sdata[t] = tsum;
    __syncthreads();
    for (int off = 1; off < 256; off <<= 1) {
        int tmp = (t >= off) ? sdata[t - off] : 0;
        __syncthreads();
        sdata[t] += tmp;
        __syncthreads();
    }
    int texcl = sdata[t] - tsum;  // exclusive prefix of this thread within chunk
    if (base + 0 < N_NODES) incl[base + 0] = texcl + v0;
    if (base + 1 < N_NODES) incl[base + 1] = texcl + v0 + v1;
    if (base + 2 < N_NODES) incl[base + 2] = texcl + v0 + v1 + v2;
    if (base + 3 < N_NODES) incl[base + 3] = texcl + v0 + v1 + v2 + v3;
    if (t == 255) bsum[blockIdx.x] = sdata[255];
}

// ---- scan pass 2: exclusive scan of the 98 chunk totals (single block) ----
__global__ void scan2_kernel(const int* __restrict__ bsum, int* __restrict__ boffs) {
    __shared__ int sdata[128];
    int t = threadIdx.x;  // 0..127
    int v = (t < N_CHUNKS) ? bsum[t] : 0;
    sdata[t] = v;
    __syncthreads();
    for (int off = 1; off < 128; off <<= 1) {
        int tmp = (t >= off) ? sdata[t - off] : 0;
        __syncthreads();
        sdata[t] += tmp;
        __syncthreads();
    }
    if (t < N_CHUNKS) boffs[t] = sdata[t] - v;  // exclusive
}

// ---- scan pass 3: finalize exclusive row starts; init write cursors ----
__global__ void scan3_kernel(const int* __restrict__ incl, const int* __restrict__ hist,
                             const int* __restrict__ boffs, int* __restrict__ rowStart,
                             int* __restrict__ writePtr) {
    int i = blockIdx.x * blockDim.x + threadIdx.x;
    if (i < N_NODES) {
        int s = incl[i] - hist[i] + boffs[i >> 10];
        rowStart[i] = s;
        writePtr[i] = s;
    }
}

// ---- fill CSR: place src of each edge into its dst's segment ----
__global__ void fill_kernel(const int* __restrict__ src, const int* __restrict__ dst,
                            int* __restrict__ writePtr, int* __restrict__ sortedSrc) {
    int e = blockIdx.x * blockDim.x + threadIdx.x;
    if (e < N_EDGES) {
        int d = dst[e];
        int pos = atomicAdd(&writePtr[d], 1);
        sortedSrc[pos] = src[e];
    }
}

// ---- layer 1 fused: gather-mean + (mean@Wl + b + x@Wr) + L2norm + relu ----
__global__ void layer1_kernel(const float* __restrict__ x, const int* __restrict__ sortedSrc,
                              const int* __restrict__ rowStart, const int* __restrict__ hist,
                              const float* __restrict__ Wl, const float* __restrict__ bl,
                              const float* __restrict__ Wr, float* __restrict__ h) {
    int node = blockIdx.x;
    int j = threadIdx.x;  // 0..127
    __shared__ float sm[128], sx[128], sred[128];
    int s0 = rowStart[node];
    int dcount = hist[node];
    float sum = 0.0f;
    for (int i = 0; i < dcount; i++) {
        int s = sortedSrc[s0 + i];
        sum += x[(long)s * 128 + j];
    }
    float dinv = 1.0f / fmaxf((float)dcount, 1.0f);
    sm[j] = sum * dinv;
    sx[j] = x[(long)node * 128 + j];
    __syncthreads();
    float acc = bl[j];
#pragma unroll 8
    for (int k = 0; k < 128; k++) {
        acc += sm[k] * Wl[k * 128 + j] + sx[k] * Wr[k * 128 + j];
    }
    sred[j] = acc * acc;
    __syncthreads();
    for (int s = 64; s > 0; s >>= 1) {
        if (j < s) sred[j] += sred[j + s];
        __syncthreads();
    }
    float norm = fmaxf(sqrtf(sred[0]), EPSN);
    h[(long)node * 128 + j] = fmaxf(acc / norm, 0.0f);
}

// ---- layer 2 fused: gather-mean + transform + L2norm + log_softmax ----
__global__ void layer2_kernel(const float* __restrict__ h, const int* __restrict__ sortedSrc,
                              const int* __restrict__ rowStart, const int* __restrict__ hist,
                              const float* __restrict__ Wl, const float* __restrict__ bl,
                              const float* __restrict__ Wr, float* __restrict__ out) {
    int node = blockIdx.x;
    int j = threadIdx.x;  // 0..127
    __shared__ float sm[128], sh[128];
    int s0 = rowStart[node];
    int dcount = hist[node];
    float sum = 0.0f;
    for (int i = 0; i < dcount; i++) {
        int s = sortedSrc[s0 + i];
        sum += h[(long)s * 128 + j];
    }
    float dinv = 1.0f / fmaxf((float)dcount, 1.0f);
    sm[j] = sum * dinv;
    sh[j] = h[(long)node * 128 + j];
    __syncthreads();
    if (j < 64) {  // wave 0 only from here
        float o = 0.0f;
        if (j < D_OUT) {
            o = bl[j];
#pragma unroll 8
            for (int k = 0; k < 128; k++) {
                o += sm[k] * Wl[k * D_OUT + j] + sh[k] * Wr[k * D_OUT + j];
            }
        }
        float sq = (j < D_OUT) ? o * o : 0.0f;
        for (int off = 32; off; off >>= 1) sq += __shfl_xor(sq, off, 64);
        float norm = fmaxf(sqrtf(sq), EPSN);
        float v = (j < D_OUT) ? o / norm : -INFINITY;
        float m = v;
        for (int off = 32; off; off >>= 1) m = fmaxf(m, __shfl_xor(m, off, 64));
        float ex = (j < D_OUT) ? expf(v - m) : 0.0f;
        float se = ex;
        for (int off = 32; off; off >>= 1) se += __shfl_xor(se, off, 64);
        float ls = logf(se);
        if (j < D_OUT) out[(long)node * D_OUT + j] = v - m - ls;
    }
}

static inline size_t align256(size_t x) { return (x + 255) & ~(size_t)255; }

extern "C" void kernel_launch(void* const* d_in, const int* in_sizes, int n_in,
                              void* d_out, int out_size, void* d_ws, size_t ws_size,
                              hipStream_t stream) {
    const float* x   = (const float*)d_in[0];
    const int*   ei  = (const int*)d_in[1];  // [2, E] int32
    const float* Wl1 = (const float*)d_in[2];
    const float* bl1 = (const float*)d_in[3];
    const float* Wr1 = (const float*)d_in[4];
    const float* Wl2 = (const float*)d_in[5];
    const float* bl2 = (const float*)d_in[6];
    const float* Wr2 = (const float*)d_in[7];
    float* out = (float*)d_out;

    const int* src = ei;
    const int* dst = ei + N_EDGES;

    char* ws = (char*)d_ws;
    size_t off = 0;
    int* hist      = (int*)(ws + off); off += align256((size_t)N_NODES * 4);
    int* incl      = (int*)(ws + off); off += align256((size_t)N_NODES * 4);
    int* rowStart  = (int*)(ws + off); off += align256((size_t)N_NODES * 4);
    int* writePtr  = (int*)(ws + off); off += align256((size_t)N_NODES * 4);
    int* bsum      = (int*)(ws + off); off += align256((size_t)N_CHUNKS * 4);
    int* boffs     = (int*)(ws + off); off += align256((size_t)N_CHUNKS * 4);
    int* sortedSrc = (int*)(ws + off); off += align256((size_t)N_EDGES * 4);
    float* h       = (float*)(ws + off); off += align256((size_t)N_NODES * 128 * 4);

    hipMemsetAsync(hist, 0, (size_t)N_NODES * 4, stream);

    hist_kernel<<<(N_EDGES + 255) / 256, 256, 0, stream>>>(dst, hist);
    scan1_kernel<<<N_CHUNKS, 256, 0, stream>>>(hist, incl, bsum);
    scan2_kernel<<<1, 128, 0, stream>>>(bsum, boffs);
    scan3_kernel<<<(N_NODES + 255) / 256, 256, 0, stream>>>(incl, hist, boffs, rowStart, writePtr);
    fill_kernel<<<(N_EDGES + 255) / 256, 256, 0, stream>>>(src, dst, writePtr, sortedSrc);

    layer1_kernel<<<N_NODES, 128, 0, stream>>>(x, sortedSrc, rowStart, hist, Wl1, bl1, Wr1, h);
    layer2_kernel<<<N_NODES, 128, 0, stream>>>(h, sortedSrc, rowStart, hist, Wl2, bl2, Wr2, out);
}

// Round 3
// 457.126 us; speedup vs baseline: 13.5658x; 2.3650x over previous
//
#include <hip/hip_runtime.h>
#include <math.h>

#define N_NODES 100000
#define N_EDGES 1600000
#define D_IN 128
#define HIDDEN 128
#define D_OUT 40
#define EPSN 1e-12f

#define SCAN_CHUNK 1024
#define N_CHUNKS ((N_NODES + SCAN_CHUNK - 1) / SCAN_CHUNK)  // 98

typedef __attribute__((ext_vector_type(8))) short short8;
typedef __attribute__((ext_vector_type(4))) float float4v;

static __device__ inline unsigned short f2bf(float f) {
    union { float f; unsigned u; } v; v.f = f;
    unsigned r = v.u + 0x7fffu + ((v.u >> 16) & 1u);
    return (unsigned short)(r >> 16);
}
static __device__ inline float bf2f(unsigned b) {
    union { unsigned u; float f; } v; v.u = b << 16;
    return v.f;
}

// ---------------- CSR build (unchanged from round 2) ----------------
__global__ void hist_kernel(const int* __restrict__ dst, int* __restrict__ hist) {
    int e = blockIdx.x * blockDim.x + threadIdx.x;
    if (e < N_EDGES) atomicAdd(&hist[dst[e]], 1);
}

__global__ void scan1_kernel(const int* __restrict__ hist, int* __restrict__ incl,
                             int* __restrict__ bsum) {
    __shared__ int sdata[256];
    int t = threadIdx.x;
    int base = blockIdx.x * SCAN_CHUNK + t * 4;
    int v0 = 0, v1 = 0, v2 = 0, v3 = 0;
    if (base + 0 < N_NODES) v0 = hist[base + 0];
    if (base + 1 < N_NODES) v1 = hist[base + 1];
    if (base + 2 < N_NODES) v2 = hist[base + 2];
    if (base + 3 < N_NODES) v3 = hist[base + 3];
    int tsum = v0 + v1 + v2 + v3;
    sdata[t] = tsum;
    __syncthreads();
    for (int off = 1; off < 256; off <<= 1) {
        int tmp = (t >= off) ? sdata[t - off] : 0;
        __syncthreads();
        sdata[t] += tmp;
        __syncthreads();
    }
    int texcl = sdata[t] - tsum;
    if (base + 0 < N_NODES) incl[base + 0] = texcl + v0;
    if (base + 1 < N_NODES) incl[base + 1] = texcl + v0 + v1;
    if (base + 2 < N_NODES) incl[base + 2] = texcl + v0 + v1 + v2;
    if (base + 3 < N_NODES) incl[base + 3] = texcl + v0 + v1 + v2 + v3;
    if (t == 255) bsum[blockIdx.x] = sdata[255];
}

__global__ void scan2_kernel(const int* __restrict__ bsum, int* __restrict__ boffs) {
    __shared__ int sdata[128];
    int t = threadIdx.x;
    int v = (t < N_CHUNKS) ? bsum[t] : 0;
    sdata[t] = v;
    __syncthreads();
    for (int off = 1; off < 128; off <<= 1) {
        int tmp = (t >= off) ? sdata[t - off] : 0;
        __syncthreads();
        sdata[t] += tmp;
        __syncthreads();
    }
    if (t < N_CHUNKS) boffs[t] = sdata[t] - v;
}

__global__ void scan3_kernel(const int* __restrict__ incl, const int* __restrict__ hist,
                             const int* __restrict__ boffs, int* __restrict__ rowStart,
                             int* __restrict__ writePtr) {
    int i = blockIdx.x * blockDim.x + threadIdx.x;
    if (i < N_NODES) {
        int s = incl[i] - hist[i] + boffs[i >> 10];
        rowStart[i] = s;
        writePtr[i] = s;
    }
}

__global__ void fill_kernel(const int* __restrict__ src, const int* __restrict__ dst,
                            int* __restrict__ writePtr, int* __restrict__ sortedSrc) {
    int e = blockIdx.x * blockDim.x + threadIdx.x;
    if (e < N_EDGES) {
        int d = dst[e];
        int pos = atomicAdd(&writePtr[d], 1);
        sortedSrc[pos] = src[e];
    }
}

// ---------------- precision / layout prep ----------------
// x fp32 -> bf16 pairs packed in u32
__global__ void cast_kernel(const float* __restrict__ x, unsigned* __restrict__ xb) {
    int tid = blockIdx.x * blockDim.x + threadIdx.x;
    if (tid < N_NODES * 64) {
        float a = x[2 * tid], b = x[2 * tid + 1];
        xb[tid] = (unsigned)f2bf(a) | ((unsigned)f2bf(b) << 16);
    }
}

// Swizzle W_cat = [Wl; Wr] (K=256 x NOUT) into MFMA B-fragment order:
// out[((kt*NC + c)*4 + quad)*16*8 + l15*8 + j] = W_cat[kt*32+quad*8+j][c*16+l15]
__global__ void swz_kernel(const float* __restrict__ Wl, const float* __restrict__ Wr,
                           unsigned short* __restrict__ out, int NC, int NOUT) {
    int idx = blockIdx.x * blockDim.x + threadIdx.x;
    int total = 8 * NC * 4 * 16 * 8;
    if (idx >= total) return;
    int j = idx & 7, l15 = (idx >> 3) & 15, quad = (idx >> 7) & 3;
    int rem = idx >> 9;
    int c = rem % NC, kt = rem / NC;
    int k = kt * 32 + quad * 8 + j;
    int n = c * 16 + l15;
    float val = 0.0f;
    if (n < NOUT) val = (k < 128) ? Wl[k * NOUT + n] : Wr[(k - 128) * NOUT + n];
    out[idx] = f2bf(val);
}

// ---------------- gather-mean: one wave per node, bf16 rows ----------------
__global__ void agg_kernel(const unsigned* __restrict__ feat,  // [N][64] u32 (2 bf16)
                           const int* __restrict__ sortedSrc,
                           const int* __restrict__ rowStart, const int* __restrict__ hist,
                           unsigned* __restrict__ meanb) {
    int w = __builtin_amdgcn_readfirstlane((int)(threadIdx.x >> 6));
    int node = blockIdx.x * 4 + w;
    int l = threadIdx.x & 63;
    int s0 = __builtin_amdgcn_readfirstlane(rowStart[node]);
    int cnt = __builtin_amdgcn_readfirstlane(hist[node]);
    float ax = 0.0f, ay = 0.0f;
    int i = 0;
    for (; i + 4 <= cnt; i += 4) {
        int sA = sortedSrc[s0 + i + 0];
        int sB = sortedSrc[s0 + i + 1];
        int sC = sortedSrc[s0 + i + 2];
        int sD = sortedSrc[s0 + i + 3];
        unsigned vA = feat[(size_t)sA * 64 + l];
        unsigned vB = feat[(size_t)sB * 64 + l];
        unsigned vC = feat[(size_t)sC * 64 + l];
        unsigned vD = feat[(size_t)sD * 64 + l];
        ax += bf2f(vA & 0xffffu) + bf2f(vB & 0xffffu) + bf2f(vC & 0xffffu) + bf2f(vD & 0xffffu);
        ay += bf2f(vA >> 16) + bf2f(vB >> 16) + bf2f(vC >> 16) + bf2f(vD >> 16);
    }
    for (; i < cnt; i++) {
        int s = sortedSrc[s0 + i];
        unsigned v = feat[(size_t)s * 64 + l];
        ax += bf2f(v & 0xffffu);
        ay += bf2f(v >> 16);
    }
    float dinv = 1.0f / fmaxf((float)cnt, 1.0f);
    meanb[(size_t)node * 64 + l] =
        (unsigned)f2bf(ax * dinv) | ((unsigned)f2bf(ay * dinv) << 16);
}

// ---------------- layer 1 GEMM + L2norm + relu (MFMA) ----------------
// C[64 nodes x 128 cols] per block; K=256 = [mean | x]; no __syncthreads.
__global__ __launch_bounds__(256) void gemm1_kernel(
    const unsigned short* __restrict__ meanb, const unsigned short* __restrict__ xb,
    const short* __restrict__ bswz, const float* __restrict__ bias,
    unsigned short* __restrict__ hb) {
    int w = __builtin_amdgcn_readfirstlane((int)(threadIdx.x >> 6));
    int lane = threadIdx.x & 63;
    int l15 = lane & 15, quad = lane >> 4;
    int n0 = blockIdx.x * 64;
    int nodeA = n0 + w * 16 + l15;
    if (nodeA >= N_NODES) nodeA = N_NODES - 1;

    float4v acc[8];
#pragma unroll
    for (int c = 0; c < 8; c++) acc[c] = (float4v){0.f, 0.f, 0.f, 0.f};

#pragma unroll
    for (int kt = 0; kt < 8; kt++) {
        const unsigned short* ab = (kt < 4) ? meanb : xb;
        int koff = (kt & 3) * 32 + quad * 8;
        short8 a = *(const short8*)(ab + (size_t)nodeA * 128 + koff);
#pragma unroll
        for (int c = 0; c < 8; c++) {
            short8 b = *(const short8*)(bswz + (((kt * 8 + c) * 4 + quad) * 16 + l15) * 8);
            acc[c] = __builtin_amdgcn_mfma_f32_16x16x32_bf16(a, b, acc[c], 0, 0, 0);
        }
    }

    // epilogue: bias, row L2-norm, relu, store bf16
    float v[8][4];
    float ss[4] = {0.f, 0.f, 0.f, 0.f};
#pragma unroll
    for (int c = 0; c < 8; c++) {
        float bi = bias[c * 16 + l15];
#pragma unroll
        for (int r = 0; r < 4; r++) {
            float t = acc[c][r] + bi;
            v[c][r] = t;
            ss[r] += t * t;
        }
    }
#pragma unroll
    for (int r = 0; r < 4; r++)
        for (int off = 1; off < 16; off <<= 1) ss[r] += __shfl_xor(ss[r], off, 64);
#pragma unroll
    for (int r = 0; r < 4; r++) {
        int node = n0 + w * 16 + quad * 4 + r;
        if (node < N_NODES) {
            float inv = 1.0f / fmaxf(sqrtf(ss[r]), EPSN);
#pragma unroll
            for (int c = 0; c < 8; c++) {
                hb[(size_t)node * 128 + c * 16 + l15] = f2bf(fmaxf(v[c][r] * inv, 0.0f));
            }
        }
    }
}

// ---------------- layer 2 GEMM + L2norm + log_softmax (MFMA) ----------------
// C[64 nodes x 48 cols(40 real)] per block; K=256 = [mean2 | h].
__global__ __launch_bounds__(256) void gemm2_kernel(
    const unsigned short* __restrict__ meanb, const unsigned short* __restrict__ hb,
    const short* __restrict__ bswz, const float* __restrict__ bias,
    float* __restrict__ out) {
    int w = __builtin_amdgcn_readfirstlane((int)(threadIdx.x >> 6));
    int lane = threadIdx.x & 63;
    int l15 = lane & 15, quad = lane >> 4;
    int n0 = blockIdx.x * 64;
    int nodeA = n0 + w * 16 + l15;
    if (nodeA >= N_NODES) nodeA = N_NODES - 1;

    float4v acc[3];
#pragma unroll
    for (int c = 0; c < 3; c++) acc[c] = (float4v){0.f, 0.f, 0.f, 0.f};

#pragma unroll
    for (int kt = 0; kt < 8; kt++) {
        const unsigned short* ab = (kt < 4) ? meanb : hb;
        int koff = (kt & 3) * 32 + quad * 8;
        short8 a = *(const short8*)(ab + (size_t)nodeA * 128 + koff);
#pragma unroll
        for (int c = 0; c < 3; c++) {
            short8 b = *(const short8*)(bswz + (((kt * 3 + c) * 4 + quad) * 16 + l15) * 8);
            acc[c] = __builtin_amdgcn_mfma_f32_16x16x32_bf16(a, b, acc[c], 0, 0, 0);
        }
    }

    float v[3][4];
    float ss[4] = {0.f, 0.f, 0.f, 0.f};
#pragma unroll
    for (int c = 0; c < 3; c++) {
        int col = c * 16 + l15;
        float bi = (col < D_OUT) ? bias[col] : 0.0f;
#pragma unroll
        for (int r = 0; r < 4; r++) {
            float t = acc[c][r] + bi;
            v[c][r] = t;
            ss[r] += t * t;
        }
    }
#pragma unroll
    for (int r = 0; r < 4; r++)
        for (int off = 1; off < 16; off <<= 1) ss[r] += __shfl_xor(ss[r], off, 64);

#pragma unroll
    for (int r = 0; r < 4; r++) {
        int node = n0 + w * 16 + quad * 4 + r;
        float inv = 1.0f / fmaxf(sqrtf(ss[r]), EPSN);
        float vn[3];
        float m = -INFINITY;
#pragma unroll
        for (int c = 0; c < 3; c++) {
            int col = c * 16 + l15;
            vn[c] = v[c][r] * inv;
            if (col < D_OUT) m = fmaxf(m, vn[c]);
        }
        for (int off = 1; off < 16; off <<= 1) m = fmaxf(m, __shfl_xor(m, off, 64));
        float se = 0.0f;
#pragma unroll
        for (int c = 0; c < 3; c++) {
            int col = c * 16 + l15;
            if (col < D_OUT) se += expf(vn[c] - m);
        }
        for (int off = 1; off < 16; off <<= 1) se += __shfl_xor(se, off, 64);
        float ls = logf(se);
        if (node < N_NODES) {
#pragma unroll
            for (int c = 0; c < 3; c++) {
                int col = c * 16 + l15;
                if (col < D_OUT) out[(size_t)node * D_OUT + col] = vn[c] - m - ls;
            }
        }
    }
}

static inline size_t align256(size_t x) { return (x + 255) & ~(size_t)255; }

extern "C" void kernel_launch(void* const* d_in, const int* in_sizes, int n_in,
                              void* d_out, int out_size, void* d_ws, size_t ws_size,
                              hipStream_t stream) {
    const float* x   = (const float*)d_in[0];
    const int*   ei  = (const int*)d_in[1];
    const float* Wl1 = (const float*)d_in[2];
    const float* bl1 = (const float*)d_in[3];
    const float* Wr1 = (const float*)d_in[4];
    const float* Wl2 = (const float*)d_in[5];
    const float* bl2 = (const float*)d_in[6];
    const float* Wr2 = (const float*)d_in[7];
    float* out = (float*)d_out;

    const int* src = ei;
    const int* dst = ei + N_EDGES;

    char* ws = (char*)d_ws;
    size_t off = 0;
    int* hist      = (int*)(ws + off); off += align256((size_t)N_NODES * 4);
    int* incl      = (int*)(ws + off); off += align256((size_t)N_NODES * 4);
    int* rowStart  = (int*)(ws + off); off += align256((size_t)N_NODES * 4);
    int* writePtr  = (int*)(ws + off); off += align256((size_t)N_NODES * 4);
    int* bsum      = (int*)(ws + off); off += align256((size_t)N_CHUNKS * 4);
    int* boffs     = (int*)(ws + off); off += align256((size_t)N_CHUNKS * 4);
    int* sortedSrc = (int*)(ws + off); off += align256((size_t)N_EDGES * 4);
    unsigned* xb     = (unsigned*)(ws + off); off += align256((size_t)N_NODES * 128 * 2);
    unsigned* meanb  = (unsigned*)(ws + off); off += align256((size_t)N_NODES * 128 * 2);
    unsigned* hb     = (unsigned*)(ws + off); off += align256((size_t)N_NODES * 128 * 2);
    unsigned short* bswz1 = (unsigned short*)(ws + off); off += align256((size_t)8 * 8 * 4 * 16 * 8 * 2);
    unsigned short* bswz2 = (unsigned short*)(ws + off); off += align256((size_t)8 * 3 * 4 * 16 * 8 * 2);

    hipMemsetAsync(hist, 0, (size_t)N_NODES * 4, stream);

    hist_kernel<<<(N_EDGES + 255) / 256, 256, 0, stream>>>(dst, hist);
    scan1_kernel<<<N_CHUNKS, 256, 0, stream>>>(hist, incl, bsum);
    scan2_kernel<<<1, 128, 0, stream>>>(bsum, boffs);
    scan3_kernel<<<(N_NODES + 255) / 256, 256, 0, stream>>>(incl, hist, boffs, rowStart, writePtr);
    fill_kernel<<<(N_EDGES + 255) / 256, 256, 0, stream>>>(src, dst, writePtr, sortedSrc);

    cast_kernel<<<(N_NODES * 64 + 255) / 256, 256, 0, stream>>>(x, xb);
    swz_kernel<<<(8 * 8 * 4 * 16 * 8 + 255) / 256, 256, 0, stream>>>(Wl1, Wr1, bswz1, 8, HIDDEN);
    swz_kernel<<<(8 * 3 * 4 * 16 * 8 + 255) / 256, 256, 0, stream>>>(Wl2, Wr2, bswz2, 3, D_OUT);

    // layer 1
    agg_kernel<<<N_NODES / 4, 256, 0, stream>>>(xb, sortedSrc, rowStart, hist, meanb);
    gemm1_kernel<<<(N_NODES + 63) / 64, 256, 0, stream>>>(
        (const unsigned short*)meanb, (const unsigned short*)xb, (const short*)bswz1, bl1,
        (unsigned short*)hb);

    // layer 2
    agg_kernel<<<N_NODES / 4, 256, 0, stream>>>(hb, sortedSrc, rowStart, hist, meanb);
    gemm2_kernel<<<(N_NODES + 63) / 64, 256, 0, stream>>>(
        (const unsigned short*)meanb, (const unsigned short*)hb, (const short*)bswz2, bl2, out);
}

// Round 4
// 334.288 us; speedup vs baseline: 18.5506x; 1.3675x over previous
//
#include <hip/hip_runtime.h>
#include <math.h>

#define N_NODES 100000
#define N_EDGES 1600000
#define D_IN 128
#define HIDDEN 128
#define D_OUT 40
#define EPSN 1e-12f

// bucket = dst >> 8 (256 nodes per bucket)
#define NBUCK 391           // ceil(100000/256)
#define EPB 4096            // edges per partition block
#define NPART ((N_EDGES + EPB - 1) / EPB)  // 391

typedef __attribute__((ext_vector_type(8))) short short8;
typedef __attribute__((ext_vector_type(4))) float float4v;

static __device__ inline unsigned short f2bf(float f) {
    union { float f; unsigned u; } v; v.f = f;
    unsigned r = v.u + 0x7fffu + ((v.u >> 16) & 1u);
    return (unsigned short)(r >> 16);
}
static __device__ inline float bf2f(unsigned b) {
    union { unsigned u; float f; } v; v.u = b << 16;
    return v.f;
}

// ---------------- bucket histogram (LDS-staged) ----------------
__global__ void bhist_kernel(const int* __restrict__ dst, int* __restrict__ bucketCount) {
    __shared__ int h[NBUCK];
    for (int i = threadIdx.x; i < NBUCK; i += 256) h[i] = 0;
    __syncthreads();
    int es = blockIdx.x * EPB;
    int ee = min(es + EPB, N_EDGES);
    for (int i = es + threadIdx.x; i < ee; i += 256) atomicAdd(&h[dst[i] >> 8], 1);
    __syncthreads();
    for (int i = threadIdx.x; i < NBUCK; i += 256)
        if (h[i]) atomicAdd(&bucketCount[i], h[i]);
}

// ---------------- scan 391 bucket counts (one block) ----------------
__global__ void bscan_kernel(const int* __restrict__ bc, int* __restrict__ bstart,
                             int* __restrict__ cursor) {
    __shared__ int s[256];
    int t = threadIdx.x;
    int a = (2 * t < NBUCK) ? bc[2 * t] : 0;
    int b = (2 * t + 1 < NBUCK) ? bc[2 * t + 1] : 0;
    int tp = a + b;
    s[t] = tp;
    __syncthreads();
    for (int off = 1; off < 256; off <<= 1) {
        int tmp = (t >= off) ? s[t - off] : 0;
        __syncthreads();
        s[t] += tmp;
        __syncthreads();
    }
    int texcl = s[t] - tp;
    if (2 * t < NBUCK) { bstart[2 * t] = texcl; cursor[2 * t] = texcl; }
    if (2 * t + 1 < NBUCK) { bstart[2 * t + 1] = texcl + a; cursor[2 * t + 1] = texcl + a; }
    if (t == 255) bstart[NBUCK] = s[255];
}

// ---------------- partition edges into buckets (packed u32) ----------------
__global__ void bpart_kernel(const int* __restrict__ src, const int* __restrict__ dst,
                             int* __restrict__ cursor, unsigned* __restrict__ pairs) {
    __shared__ int h[NBUCK];
    __shared__ int base[NBUCK];
    int t = threadIdx.x;
    for (int i = t; i < NBUCK; i += 256) h[i] = 0;
    __syncthreads();
    int es = blockIdx.x * EPB;
    int ee = min(es + EPB, N_EDGES);
    for (int i = es + t; i < ee; i += 256) atomicAdd(&h[dst[i] >> 8], 1);
    __syncthreads();
    for (int i = t; i < NBUCK; i += 256) {
        int c = h[i];
        base[i] = c ? atomicAdd(&cursor[i], c) : 0;
    }
    __syncthreads();
    for (int i = t; i < NBUCK; i += 256) h[i] = 0;
    __syncthreads();
    for (int i = es + t; i < ee; i += 256) {
        int d = dst[i];
        int bk = d >> 8;
        int r = atomicAdd(&h[bk], 1);
        pairs[base[bk] + r] = ((unsigned)src[i] << 8) | (unsigned)(d & 255);
    }
}

// ---------------- per-bucket CSR finalize: count+scan+fill all in LDS ----------------
__global__ void csr_kernel(const unsigned* __restrict__ pairs, const int* __restrict__ bstart,
                           int* __restrict__ hist, int* __restrict__ rowStart,
                           int* __restrict__ sortedSrc) {
    __shared__ int cnt[256];
    __shared__ int sc[256];
    __shared__ int cur[256];
    int b = blockIdx.x, t = threadIdx.x;
    int es = bstart[b], ee = bstart[b + 1];
    cnt[t] = 0;
    __syncthreads();
    for (int i = es + t; i < ee; i += 256) atomicAdd(&cnt[pairs[i] & 255], 1);
    __syncthreads();
    int v = cnt[t];
    sc[t] = v;
    __syncthreads();
    for (int off = 1; off < 256; off <<= 1) {
        int tmp = (t >= off) ? sc[t - off] : 0;
        __syncthreads();
        sc[t] += tmp;
        __syncthreads();
    }
    int excl = sc[t] - v;
    int node = (b << 8) + t;
    if (node < N_NODES) {
        hist[node] = v;
        rowStart[node] = es + excl;
    }
    cur[t] = excl;
    __syncthreads();
    for (int i = es + t; i < ee; i += 256) {
        unsigned p = pairs[i];
        int r = atomicAdd(&cur[p & 255], 1);
        sortedSrc[es + r] = (int)(p >> 8);
    }
}

// ---------------- precision / layout prep ----------------
__global__ void cast_kernel(const float* __restrict__ x, unsigned* __restrict__ xb) {
    int tid = blockIdx.x * blockDim.x + threadIdx.x;
    if (tid < N_NODES * 64) {
        float a = x[2 * tid], b = x[2 * tid + 1];
        xb[tid] = (unsigned)f2bf(a) | ((unsigned)f2bf(b) << 16);
    }
}

__global__ void swz_kernel(const float* __restrict__ Wl, const float* __restrict__ Wr,
                           unsigned short* __restrict__ out, int NC, int NOUT) {
    int idx = blockIdx.x * blockDim.x + threadIdx.x;
    int total = 8 * NC * 4 * 16 * 8;
    if (idx >= total) return;
    int j = idx & 7, l15 = (idx >> 3) & 15, quad = (idx >> 7) & 3;
    int rem = idx >> 9;
    int c = rem % NC, kt = rem / NC;
    int k = kt * 32 + quad * 8 + j;
    int n = c * 16 + l15;
    float val = 0.0f;
    if (n < NOUT) val = (k < 128) ? Wl[k * NOUT + n] : Wr[(k - 128) * NOUT + n];
    out[idx] = f2bf(val);
}

// ---------------- gather-mean: one wave per node, uint2 loads, 2 edges/iter ----------------
__global__ void agg_kernel(const uint2* __restrict__ feat,  // [N][32] uint2 (4 bf16)
                           const int* __restrict__ sortedSrc,
                           const int* __restrict__ rowStart, const int* __restrict__ hist,
                           uint2* __restrict__ meanb) {
    int w = __builtin_amdgcn_readfirstlane((int)(threadIdx.x >> 6));
    int node = blockIdx.x * 4 + w;
    int lane = threadIdx.x & 63;
    int half = lane >> 5, sl = lane & 31;
    int s0 = __builtin_amdgcn_readfirstlane(rowStart[node]);
    int cnt = __builtin_amdgcn_readfirstlane(hist[node]);
    float a0 = 0.f, a1 = 0.f, a2 = 0.f, a3 = 0.f;
    int i = 0;
    for (; i + 8 <= cnt; i += 8) {
        int sA = sortedSrc[s0 + i + 0 + half];
        int sB = sortedSrc[s0 + i + 2 + half];
        int sC = sortedSrc[s0 + i + 4 + half];
        int sD = sortedSrc[s0 + i + 6 + half];
        uint2 vA = feat[(size_t)sA * 32 + sl];
        uint2 vB = feat[(size_t)sB * 32 + sl];
        uint2 vC = feat[(size_t)sC * 32 + sl];
        uint2 vD = feat[(size_t)sD * 32 + sl];
        a0 += bf2f(vA.x & 0xffffu) + bf2f(vB.x & 0xffffu) + bf2f(vC.x & 0xffffu) + bf2f(vD.x & 0xffffu);
        a1 += bf2f(vA.x >> 16) + bf2f(vB.x >> 16) + bf2f(vC.x >> 16) + bf2f(vD.x >> 16);
        a2 += bf2f(vA.y & 0xffffu) + bf2f(vB.y & 0xffffu) + bf2f(vC.y & 0xffffu) + bf2f(vD.y & 0xffffu);
        a3 += bf2f(vA.y >> 16) + bf2f(vB.y >> 16) + bf2f(vC.y >> 16) + bf2f(vD.y >> 16);
    }
    for (; i + 2 <= cnt; i += 2) {
        int s = sortedSrc[s0 + i + half];
        uint2 v = feat[(size_t)s * 32 + sl];
        a0 += bf2f(v.x & 0xffffu);
        a1 += bf2f(v.x >> 16);
        a2 += bf2f(v.y & 0xffffu);
        a3 += bf2f(v.y >> 16);
    }
    if (i < cnt && half == 0) {  // odd tail: half-0 lanes cover the full row
        int s = sortedSrc[s0 + i];
        uint2 v = feat[(size_t)s * 32 + sl];
        a0 += bf2f(v.x & 0xffffu);
        a1 += bf2f(v.x >> 16);
        a2 += bf2f(v.y & 0xffffu);
        a3 += bf2f(v.y >> 16);
    }
    // combine the two halves
    a0 += __shfl_xor(a0, 32, 64);
    a1 += __shfl_xor(a1, 32, 64);
    a2 += __shfl_xor(a2, 32, 64);
    a3 += __shfl_xor(a3, 32, 64);
    if (half == 0) {
        float dinv = 1.0f / fmaxf((float)cnt, 1.0f);
        uint2 o;
        o.x = (unsigned)f2bf(a0 * dinv) | ((unsigned)f2bf(a1 * dinv) << 16);
        o.y = (unsigned)f2bf(a2 * dinv) | ((unsigned)f2bf(a3 * dinv) << 16);
        meanb[(size_t)node * 32 + sl] = o;
    }
}

// ---------------- layer 1 GEMM + L2norm + relu (MFMA) ----------------
__global__ __launch_bounds__(256) void gemm1_kernel(
    const unsigned short* __restrict__ meanb, const unsigned short* __restrict__ xb,
    const short* __restrict__ bswz, const float* __restrict__ bias,
    unsigned short* __restrict__ hb) {
    int w = __builtin_amdgcn_readfirstlane((int)(threadIdx.x >> 6));
    int lane = threadIdx.x & 63;
    int l15 = lane & 15, quad = lane >> 4;
    int n0 = blockIdx.x * 64;
    int nodeA = n0 + w * 16 + l15;
    if (nodeA >= N_NODES) nodeA = N_NODES - 1;

    float4v acc[8];
#pragma unroll
    for (int c = 0; c < 8; c++) acc[c] = (float4v){0.f, 0.f, 0.f, 0.f};

#pragma unroll
    for (int kt = 0; kt < 8; kt++) {
        const unsigned short* ab = (kt < 4) ? meanb : xb;
        int koff = (kt & 3) * 32 + quad * 8;
        short8 a = *(const short8*)(ab + (size_t)nodeA * 128 + koff);
#pragma unroll
        for (int c = 0; c < 8; c++) {
            short8 b = *(const short8*)(bswz + (((kt * 8 + c) * 4 + quad) * 16 + l15) * 8);
            acc[c] = __builtin_amdgcn_mfma_f32_16x16x32_bf16(a, b, acc[c], 0, 0, 0);
        }
    }

    float v[8][4];
    float ss[4] = {0.f, 0.f, 0.f, 0.f};
#pragma unroll
    for (int c = 0; c < 8; c++) {
        float bi = bias[c * 16 + l15];
#pragma unroll
        for (int r = 0; r < 4; r++) {
            float t = acc[c][r] + bi;
            v[c][r] = t;
            ss[r] += t * t;
        }
    }
#pragma unroll
    for (int r = 0; r < 4; r++)
        for (int off = 1; off < 16; off <<= 1) ss[r] += __shfl_xor(ss[r], off, 64);
#pragma unroll
    for (int r = 0; r < 4; r++) {
        int node = n0 + w * 16 + quad * 4 + r;
        if (node < N_NODES) {
            float inv = 1.0f / fmaxf(sqrtf(ss[r]), EPSN);
#pragma unroll
            for (int c = 0; c < 8; c++) {
                hb[(size_t)node * 128 + c * 16 + l15] = f2bf(fmaxf(v[c][r] * inv, 0.0f));
            }
        }
    }
}

// ---------------- layer 2 GEMM + L2norm + log_softmax (MFMA) ----------------
__global__ __launch_bounds__(256) void gemm2_kernel(
    const unsigned short* __restrict__ meanb, const unsigned short* __restrict__ hb,
    const short* __restrict__ bswz, const float* __restrict__ bias,
    float* __restrict__ out) {
    int w = __builtin_amdgcn_readfirstlane((int)(threadIdx.x >> 6));
    int lane = threadIdx.x & 63;
    int l15 = lane & 15, quad = lane >> 4;
    int n0 = blockIdx.x * 64;
    int nodeA = n0 + w * 16 + l15;
    if (nodeA >= N_NODES) nodeA = N_NODES - 1;

    float4v acc[3];
#pragma unroll
    for (int c = 0; c < 3; c++) acc[c] = (float4v){0.f, 0.f, 0.f, 0.f};

#pragma unroll
    for (int kt = 0; kt < 8; kt++) {
        const unsigned short* ab = (kt < 4) ? meanb : hb;
        int koff = (kt & 3) * 32 + quad * 8;
        short8 a = *(const short8*)(ab + (size_t)nodeA * 128 + koff);
#pragma unroll
        for (int c = 0; c < 3; c++) {
            short8 b = *(const short8*)(bswz + (((kt * 3 + c) * 4 + quad) * 16 + l15) * 8);
            acc[c] = __builtin_amdgcn_mfma_f32_16x16x32_bf16(a, b, acc[c], 0, 0, 0);
        }
    }

    float v[3][4];
    float ss[4] = {0.f, 0.f, 0.f, 0.f};
#pragma unroll
    for (int c = 0; c < 3; c++) {
        int col = c * 16 + l15;
        float bi = (col < D_OUT) ? bias[col] : 0.0f;
#pragma unroll
        for (int r = 0; r < 4; r++) {
            float t = acc[c][r] + bi;
            v[c][r] = t;
            ss[r] += t * t;
        }
    }
#pragma unroll
    for (int r = 0; r < 4; r++)
        for (int off = 1; off < 16; off <<= 1) ss[r] += __shfl_xor(ss[r], off, 64);

#pragma unroll
    for (int r = 0; r < 4; r++) {
        int node = n0 + w * 16 + quad * 4 + r;
        float inv = 1.0f / fmaxf(sqrtf(ss[r]), EPSN);
        float vn[3];
        float m = -INFINITY;
#pragma unroll
        for (int c = 0; c < 3; c++) {
            int col = c * 16 + l15;
            vn[c] = v[c][r] * inv;
            if (col < D_OUT) m = fmaxf(m, vn[c]);
        }
        for (int off = 1; off < 16; off <<= 1) m = fmaxf(m, __shfl_xor(m, off, 64));
        float se = 0.0f;
#pragma unroll
        for (int c = 0; c < 3; c++) {
            int col = c * 16 + l15;
            if (col < D_OUT) se += expf(vn[c] - m);
        }
        for (int off = 1; off < 16; off <<= 1) se += __shfl_xor(se, off, 64);
        float ls = logf(se);
        if (node < N_NODES) {
#pragma unroll
            for (int c = 0; c < 3; c++) {
                int col = c * 16 + l15;
                if (col < D_OUT) out[(size_t)node * D_OUT + col] = vn[c] - m - ls;
            }
        }
    }
}

static inline size_t align256(size_t x) { return (x + 255) & ~(size_t)255; }

extern "C" void kernel_launch(void* const* d_in, const int* in_sizes, int n_in,
                              void* d_out, int out_size, void* d_ws, size_t ws_size,
                              hipStream_t stream) {
    const float* x   = (const float*)d_in[0];
    const int*   ei  = (const int*)d_in[1];
    const float* Wl1 = (const float*)d_in[2];
    const float* bl1 = (const float*)d_in[3];
    const float* Wr1 = (const float*)d_in[4];
    const float* Wl2 = (const float*)d_in[5];
    const float* bl2 = (const float*)d_in[6];
    const float* Wr2 = (const float*)d_in[7];
    float* out = (float*)d_out;

    const int* src = ei;
    const int* dst = ei + N_EDGES;

    char* ws = (char*)d_ws;
    size_t off = 0;
    int* bucketCount = (int*)(ws + off); off += align256((size_t)NBUCK * 4);
    int* bucketStart = (int*)(ws + off); off += align256((size_t)(NBUCK + 1) * 4);
    int* cursor      = (int*)(ws + off); off += align256((size_t)NBUCK * 4);
    int* hist        = (int*)(ws + off); off += align256((size_t)N_NODES * 4);
    int* rowStart    = (int*)(ws + off); off += align256((size_t)N_NODES * 4);
    unsigned* pairs  = (unsigned*)(ws + off); off += align256((size_t)N_EDGES * 4);
    int* sortedSrc   = (int*)(ws + off); off += align256((size_t)N_EDGES * 4);
    unsigned* xb     = (unsigned*)(ws + off); off += align256((size_t)N_NODES * 128 * 2);
    unsigned* meanb  = (unsigned*)(ws + off); off += align256((size_t)N_NODES * 128 * 2);
    unsigned* hb     = (unsigned*)(ws + off); off += align256((size_t)N_NODES * 128 * 2);
    unsigned short* bswz1 = (unsigned short*)(ws + off); off += align256((size_t)8 * 8 * 4 * 16 * 8 * 2);
    unsigned short* bswz2 = (unsigned short*)(ws + off); off += align256((size_t)8 * 3 * 4 * 16 * 8 * 2);

    hipMemsetAsync(bucketCount, 0, (size_t)NBUCK * 4, stream);

    bhist_kernel<<<NPART, 256, 0, stream>>>(dst, bucketCount);
    bscan_kernel<<<1, 256, 0, stream>>>(bucketCount, bucketStart, cursor);
    bpart_kernel<<<NPART, 256, 0, stream>>>(src, dst, cursor, pairs);
    csr_kernel<<<NBUCK, 256, 0, stream>>>(pairs, bucketStart, hist, rowStart, sortedSrc);

    cast_kernel<<<(N_NODES * 64 + 255) / 256, 256, 0, stream>>>(x, xb);
    swz_kernel<<<(8 * 8 * 4 * 16 * 8 + 255) / 256, 256, 0, stream>>>(Wl1, Wr1, bswz1, 8, HIDDEN);
    swz_kernel<<<(8 * 3 * 4 * 16 * 8 + 255) / 256, 256, 0, stream>>>(Wl2, Wr2, bswz2, 3, D_OUT);

    // layer 1
    agg_kernel<<<N_NODES / 4, 256, 0, stream>>>((const uint2*)xb, sortedSrc, rowStart, hist,
                                                (uint2*)meanb);
    gemm1_kernel<<<(N_NODES + 63) / 64, 256, 0, stream>>>(
        (const unsigned short*)meanb, (const unsigned short*)xb, (const short*)bswz1, bl1,
        (unsigned short*)hb);

    // layer 2
    agg_kernel<<<N_NODES / 4, 256, 0, stream>>>((const uint2*)hb, sortedSrc, rowStart, hist,
                                                (uint2*)meanb);
    gemm2_kernel<<<(N_NODES + 63) / 64, 256, 0, stream>>>(
        (const unsigned short*)meanb, (const unsigned short*)hb, (const short*)bswz2, bl2, out);
}